// Round 1
// baseline (42547.870 us; speedup 1.0000x reference)
//
#include <hip/hip_runtime.h>
#include <hip/hip_bf16.h>

// ---------------- problem constants ----------------
// LP=500, LQ=64, B=64, D=256, H=150
#define LP 500
#define NB 64     // batch
#define ND 256    // D
#define NH 150    // H
#define NJ 512    // g columns we need (rows 512..1023 of Wg)

// ---------------- workspace layout (floats) ----------------
// all offsets multiples of 64 floats (256B) -> float4 aligned
constexpr size_t OFF_SYNC = 0;          // 64 uints
constexpr size_t OFF_VT   = 64;         // vT[h][b]      150*64
constexpr size_t OFF_YB   = 9664;       // yB[b][h]      64*150
constexpr size_t OFF_GHT  = 19264;      // ghT[m][b]     450*64
constexpr size_t OFF_CCT  = 48064;      // ccT[d][b]     256*64
constexpr size_t OFF_CT   = 64448;      // cT[k][b]      512*64
constexpr size_t OFF_WPF  = 97216;      // Wpf[h][d]     150*256
constexpr size_t OFF_WQF  = 135616;     // Wqf[h][d]     150*256
constexpr size_t OFF_WG1  = 174016;     // Wg1[j][d]     512*256 (u-part fold)
constexpr size_t OFF_WGF  = 305088;     // Wgf[j][d]     512*256 (cc-part fold)
constexpr size_t OFF_WUQ  = 436160;     // Wuq[q][b][h]  64*64*150
constexpr size_t OFF_P1   = 1050560;    // P1[t][b][h]   500*64*150
constexpr size_t OFF_UPT  = 5850560;    // UpT[t][d][b]  500*256*64
constexpr size_t OFF_UQT  = 14042560;   // UqT[q][d][b]  64*256*64
constexpr size_t OFF_GUT  = 15091136;   // GuT[t][j][b]  bf16 500*512*64 (as 8192000 floats)
constexpr size_t WS_FLOATS = 23283136;  // ~93.1 MB

// ---------------- helpers ----------------
__device__ __forceinline__ float fast_rcp(float x) { return __builtin_amdgcn_rcpf(x); }
__device__ __forceinline__ float sigm(float x)   { return fast_rcp(1.f + __expf(-x)); }
__device__ __forceinline__ float tanh_f(float x) { return 1.f - 2.f * fast_rcp(1.f + __expf(2.f * x)); }

// grid barrier: 8 sub-counters + root + epoch. 64 blocks, 8 per sub.
__device__ __forceinline__ void gbar(unsigned* sync, unsigned target) {
    __syncthreads();
    if (threadIdx.x == 0) {
        unsigned s = blockIdx.x & 7u;
        unsigned old = __hip_atomic_fetch_add(&sync[s], 1u, __ATOMIC_ACQ_REL, __HIP_MEMORY_SCOPE_AGENT);
        if ((old & 7u) == 7u) {
            unsigned r = __hip_atomic_fetch_add(&sync[8], 1u, __ATOMIC_ACQ_REL, __HIP_MEMORY_SCOPE_AGENT);
            if ((r & 7u) == 7u) {
                __hip_atomic_store(&sync[9], (r >> 3) + 1u, __ATOMIC_RELEASE, __HIP_MEMORY_SCOPE_AGENT);
            }
        }
        while (__hip_atomic_load(&sync[9], __ATOMIC_ACQUIRE, __HIP_MEMORY_SCOPE_AGENT) < target) {
            __builtin_amdgcn_s_sleep(1);
        }
    }
    __syncthreads();
}

// ---------------- precompute kernels ----------------

// fold weights, transpose v0, zero sync
__global__ __launch_bounds__(256) void k_prep(const float* __restrict__ Wp, const float* __restrict__ Wq,
                                              const float* __restrict__ Wg, const float* __restrict__ v0,
                                              float* __restrict__ ws) {
    int i = blockIdx.x * 256 + threadIdx.x;
    if (i < 38400) { int h = i >> 8, d = i & 255; ws[OFF_WPF + i] = Wp[h * 512 + d] + Wp[h * 512 + 256 + d]; return; }
    i -= 38400;
    if (i < 38400) { int h = i >> 8, d = i & 255; ws[OFF_WQF + i] = Wq[h * 512 + d] + Wq[h * 512 + 256 + d]; return; }
    i -= 38400;
    if (i < 131072) { int j = i >> 8, d = i & 255; size_t row = (size_t)(512 + j) * 1024; ws[OFF_WG1 + i] = Wg[row + d] + Wg[row + 256 + d]; return; }
    i -= 131072;
    if (i < 131072) { int j = i >> 8, d = i & 255; size_t row = (size_t)(512 + j) * 1024; ws[OFF_WGF + i] = Wg[row + 512 + d] + Wg[row + 768 + d]; return; }
    i -= 131072;
    if (i < 9600) { int h = i >> 6, b = i & 63; ws[OFF_VT + i] = v0[b * 150 + h]; return; }
    i -= 9600;
    if (i < 16) { ((unsigned*)ws)[i] = 0u; }
}

// transpose X[t][64][256] -> XT[t][256][64], one block per t
__global__ __launch_bounds__(256) void k_tr(const float* __restrict__ X, float* __restrict__ XT) {
    __shared__ float tile[64][65];
    size_t base = (size_t)blockIdx.x * 16384;
    for (int ph = 0; ph < 4; ++ph) {
        for (int i = threadIdx.x; i < 4096; i += 256) {
            int b = i >> 6, dl = i & 63;
            tile[b][dl] = X[base + (size_t)b * 256 + ph * 64 + dl];
        }
        __syncthreads();
        for (int i = threadIdx.x; i < 4096; i += 256) {
            int d = i >> 6, bl = i & 63;
            XT[base + (size_t)(ph * 64 + d) * 64 + bl] = tile[bl][d];
        }
        __syncthreads();
    }
}

// out[t][h] over all b: acc[h,b] = sum_d XT[t,d,b]*Wf[h,d]
// mode1 (outBH != null): f32 out[t][b][Hrows] via LDS transpose (coalesced)
// mode2 (outTB != null): bf16 out[t][h][64] direct coalesced
__global__ __launch_bounds__(256) void k_gemm(const float* __restrict__ XT, const float* __restrict__ Wf,
                                              float* __restrict__ outBH, __hip_bfloat16* __restrict__ outTB,
                                              int Hrows, int tilesPerT) {
    __shared__ float OL[64 * 33];
    int bidx = blockIdx.x;
    int t = bidx / tilesPerT, tile = bidx - t * tilesPerT;
    int w = threadIdx.x >> 6, lane = threadIdx.x & 63;
    int h0 = __builtin_amdgcn_readfirstlane(tile * 32 + w * 8);
    const float* x = XT + (size_t)t * 16384;
    float acc[8];
    const float* wr[8];
#pragma unroll
    for (int r = 0; r < 8; ++r) {
        int hr = h0 + r; if (hr >= Hrows) hr = Hrows - 1;
        wr[r] = Wf + (size_t)hr * 256;
        acc[r] = 0.f;
    }
    for (int d = 0; d < 256; d += 4) {
        float cv0 = x[(d + 0) * 64 + lane];
        float cv1 = x[(d + 1) * 64 + lane];
        float cv2 = x[(d + 2) * 64 + lane];
        float cv3 = x[(d + 3) * 64 + lane];
#pragma unroll
        for (int r = 0; r < 8; ++r) {
            float4 wv = *(const float4*)(wr[r] + d);
            acc[r] += cv0 * wv.x + cv1 * wv.y + cv2 * wv.z + cv3 * wv.w;
        }
    }
    if (outTB != nullptr) {
#pragma unroll
        for (int r = 0; r < 8; ++r) {
            int hr = h0 + r;
            if (hr < Hrows) outTB[(size_t)t * Hrows * 64 + (size_t)hr * 64 + lane] = __float2bfloat16(acc[r]);
        }
    } else {
#pragma unroll
        for (int r = 0; r < 8; ++r) { int hl = w * 8 + r; OL[lane * 33 + hl] = acc[r]; }
        __syncthreads();
        int hbase = tile * 32;
        int nh = Hrows - hbase; if (nh > 32) nh = 32;
        for (int i = threadIdx.x; i < 64 * nh; i += 256) {
            int b = i / nh, hl = i - b * nh;
            outBH[(size_t)t * 64 * Hrows + (size_t)b * Hrows + hbase + hl] = OL[b * 33 + hl];
        }
    }
}

// ---------------- persistent scan kernel: 64 blocks x 256 threads ----------------
__global__ __launch_bounds__(256) void k_scan(
    const float* __restrict__ Uq, const float* __restrict__ V,
    const float* __restrict__ Wv, const float* __restrict__ Wih,
    const float* __restrict__ Whh, const float* __restrict__ bih,
    const float* __restrict__ bhh, float* __restrict__ ws,
    const __hip_bfloat16* __restrict__ GuT, float* __restrict__ out) {
    __shared__ union __align__(16) Sh {
        struct { float pb[152]; float vv[152]; float sL[64]; float aL[64]; } a;
        float ccL[16384];
        float cL[16384];
        float vL[9600];
    } sh;
    unsigned* sync = (unsigned*)ws;
    float* vT = ws + OFF_VT;
    float* yB = ws + OFF_YB;
    float* ghT = ws + OFF_GHT;
    float* ccT = ws + OFF_CCT;
    float* cT = ws + OFF_CT;
    const float* P1 = ws + OFF_P1;
    const float* Wuq = ws + OFF_WUQ;
    const float* Wgf = ws + OFF_WGF;
    const int tid = threadIdx.x, bid = blockIdx.x;
    const int w = tid >> 6, lane = tid & 63;
    unsigned bar = 0;

    for (int t = 0; t < LP; ++t) {
        // ---- Phase E: y[b,h] = v @ Wv^T ; gh[m,b] = v @ Whh^T + bhh ----
        {
            for (int i = tid; i < 2400; i += 256) ((float4*)sh.vL)[i] = ((const float4*)vT)[i];
            __syncthreads();
            int W0 = __builtin_amdgcn_readfirstlane(bid * 4 + w);  // 0..255
            const float *r0, *r1, *r2;
            float a0, a1, a2;
            float* o0;
            if (W0 < 150) { r0 = Wv + W0 * 150; o0 = nullptr; a0 = 0.f; }
            else { r0 = Whh + (W0 - 150) * 150; o0 = ghT + (size_t)(W0 - 150) * 64; a0 = bhh[W0 - 150]; }
            int m1 = W0 + 256;  // 256..511, always gh
            r1 = Whh + (m1 - 150) * 150; a1 = bhh[m1 - 150];
            float* o1 = ghT + (size_t)(m1 - 150) * 64;
            int m2 = W0 + 512;
            bool has2 = (m2 < 600);
            if (has2) { r2 = Whh + (m2 - 150) * 150; a2 = bhh[m2 - 150]; } else { r2 = Whh; a2 = 0.f; }
            float* o2 = has2 ? (ghT + (size_t)(m2 - 150) * 64) : nullptr;
            for (int hp = 0; hp < 150; hp += 2) {
                float c0 = sh.vL[hp * 64 + lane];
                float c1 = sh.vL[(hp + 1) * 64 + lane];
                float2 w0 = *(const float2*)(r0 + hp); a0 += c0 * w0.x + c1 * w0.y;
                float2 w1 = *(const float2*)(r1 + hp); a1 += c0 * w1.x + c1 * w1.y;
                float2 w2 = *(const float2*)(r2 + hp); a2 += c0 * w2.x + c1 * w2.y;
            }
            if (W0 < 150) yB[lane * 150 + W0] = a0; else o0[lane] = a0;
            o1[lane] = a1;
            if (has2) o2[lane] = a2;
        }
        gbar(sync, ++bar);
        // ---- Phase A': s, softmax, cc (one block per b) ----
        {
            const int b = bid;
            for (int i = tid; i < 150; i += 256) {
                sh.a.pb[i] = P1[(size_t)t * 9600 + b * 150 + i] + yB[b * 150 + i];
                sh.a.vv[i] = V[b * 150 + i];
            }
            __syncthreads();
            for (int q = w; q < 64; q += 4) {
                const float* wu = Wuq + (size_t)q * 9600 + b * 150;
                float part = 0.f;
                for (int i = lane; i < 150; i += 64)
                    part += tanh_f(sh.a.pb[i] + wu[i]) * sh.a.vv[i];
                part += __shfl_xor(part, 32); part += __shfl_xor(part, 16);
                part += __shfl_xor(part, 8);  part += __shfl_xor(part, 4);
                part += __shfl_xor(part, 2);  part += __shfl_xor(part, 1);
                if (lane == 0) sh.a.sL[q] = part;
            }
            __syncthreads();
            if (w == 0) {
                float s = sh.a.sL[lane];
                float m = s;
                m = fmaxf(m, __shfl_xor(m, 32)); m = fmaxf(m, __shfl_xor(m, 16));
                m = fmaxf(m, __shfl_xor(m, 8));  m = fmaxf(m, __shfl_xor(m, 4));
                m = fmaxf(m, __shfl_xor(m, 2));  m = fmaxf(m, __shfl_xor(m, 1));
                float e = __expf(s - m);
                float su = e;
                su += __shfl_xor(su, 32); su += __shfl_xor(su, 16); su += __shfl_xor(su, 8);
                su += __shfl_xor(su, 4);  su += __shfl_xor(su, 2);  su += __shfl_xor(su, 1);
                sh.a.aL[lane] = e * fast_rcp(su);
            }
            __syncthreads();
            {
                float acc = 0.f;
                const float* uqb = Uq + (size_t)b * 256 + tid;
#pragma unroll 4
                for (int q = 0; q < 64; ++q) acc += sh.a.aL[q] * uqb[(size_t)q * 16384];
                ccT[tid * 64 + b] = acc;  // [d][b]
            }
        }
        gbar(sync, ++bar);
        // ---- Phase C: g = sigm(Gu + cc.Wgf^T), c_ = g*cc ----
        {
            for (int i = tid; i < 4096; i += 256) ((float4*)sh.ccL)[i] = ((const float4*)ccT)[i];
            __syncthreads();
            int j0 = __builtin_amdgcn_readfirstlane(bid * 8 + w * 2);
            float acc0 = __bfloat162float(GuT[(size_t)t * 32768 + (size_t)j0 * 64 + lane]);
            float acc1 = __bfloat162float(GuT[(size_t)t * 32768 + (size_t)(j0 + 1) * 64 + lane]);
            const float* g0p = Wgf + (size_t)j0 * 256;
            const float* g1p = g0p + 256;
            for (int d = 0; d < 256; d += 4) {
                float c0 = sh.ccL[(d + 0) * 64 + lane];
                float c1 = sh.ccL[(d + 1) * 64 + lane];
                float c2 = sh.ccL[(d + 2) * 64 + lane];
                float c3 = sh.ccL[(d + 3) * 64 + lane];
                float4 wa = *(const float4*)(g0p + d);
                float4 wb = *(const float4*)(g1p + d);
                acc0 += c0 * wa.x + c1 * wa.y + c2 * wa.z + c3 * wa.w;
                acc1 += c0 * wb.x + c1 * wb.y + c2 * wb.z + c3 * wb.w;
            }
            float g0 = sigm(acc0), g1 = sigm(acc1);
            float cv0 = sh.ccL[(j0 & 255) * 64 + lane];
            float cv1 = sh.ccL[((j0 + 1) & 255) * 64 + lane];
            cT[(size_t)j0 * 64 + lane] = g0 * cv0;
            cT[(size_t)(j0 + 1) * 64 + lane] = g1 * cv1;
        }
        gbar(sync, ++bar);
        // ---- Phase D: gi = c_ @ Wih^T + bih ; GRU combine ; write v_new + output ----
        {
            int h = __builtin_amdgcn_readfirstlane(bid * 4 + w);
            int hc = (h < 150) ? h : 149;
            float ar = 0.f, az = 0.f, an = 0.f;
            if (bid < 38) {
                for (int pass = 0; pass < 2; ++pass) {
                    __syncthreads();
                    for (int i = tid; i < 4096; i += 256)
                        ((float4*)sh.cL)[i] = ((const float4*)(cT + pass * 16384))[i];
                    __syncthreads();
                    const float* wr4 = Wih + (size_t)hc * 512 + pass * 256;
                    const float* wz4 = Wih + (size_t)(150 + hc) * 512 + pass * 256;
                    const float* wn4 = Wih + (size_t)(300 + hc) * 512 + pass * 256;
                    for (int k = 0; k < 256; k += 4) {
                        float c0 = sh.cL[(k + 0) * 64 + lane];
                        float c1 = sh.cL[(k + 1) * 64 + lane];
                        float c2 = sh.cL[(k + 2) * 64 + lane];
                        float c3 = sh.cL[(k + 3) * 64 + lane];
                        float4 wa = *(const float4*)(wr4 + k);
                        ar += c0 * wa.x + c1 * wa.y + c2 * wa.z + c3 * wa.w;
                        float4 wb = *(const float4*)(wz4 + k);
                        az += c0 * wb.x + c1 * wb.y + c2 * wb.z + c3 * wb.w;
                        float4 wc = *(const float4*)(wn4 + k);
                        an += c0 * wc.x + c1 * wc.y + c2 * wc.z + c3 * wc.w;
                    }
                }
                if (h < 150) {
                    float rg = sigm(ar + bih[h] + ghT[(size_t)h * 64 + lane]);
                    float z  = sigm(az + bih[150 + h] + ghT[(size_t)(150 + h) * 64 + lane]);
                    float nn = tanh_f(an + bih[300 + h] + rg * ghT[(size_t)(300 + h) * 64 + lane]);
                    float vo = vT[(size_t)h * 64 + lane];
                    float vn = (1.f - z) * nn + z * vo;
                    vT[(size_t)h * 64 + lane] = vn;
                    out[(size_t)t * 9600 + (size_t)lane * 150 + h] = vn;
                }
            }
        }
        gbar(sync, ++bar);
    }
}

// ---------------- launch ----------------
extern "C" void kernel_launch(void* const* d_in, const int* in_sizes, int n_in,
                              void* d_out, int out_size, void* d_ws, size_t ws_size,
                              hipStream_t stream) {
    const float* Up  = (const float*)d_in[0];
    const float* Uq  = (const float*)d_in[1];
    const float* Wp  = (const float*)d_in[2];
    const float* Wq  = (const float*)d_in[3];
    const float* Wv  = (const float*)d_in[4];
    const float* Wg  = (const float*)d_in[5];
    const float* V   = (const float*)d_in[6];
    const float* v0  = (const float*)d_in[7];
    const float* Wih = (const float*)d_in[8];
    const float* Whh = (const float*)d_in[9];
    const float* bih = (const float*)d_in[10];
    const float* bhh = (const float*)d_in[11];
    float* out = (float*)d_out;
    float* ws = (float*)d_ws;

    if (ws_size < WS_FLOATS * sizeof(float)) {
        // workspace too small; bail (output left poisoned -> visible failure)
        return;
    }

    __hip_bfloat16* GuT = (__hip_bfloat16*)(ws + OFF_GUT);

    k_prep<<<(348560 + 255) / 256, 256, 0, stream>>>(Wp, Wq, Wg, v0, ws);
    k_tr<<<500, 256, 0, stream>>>(Up, ws + OFF_UPT);
    k_tr<<<64, 256, 0, stream>>>(Uq, ws + OFF_UQT);
    // P1[t][b][h] = Up[t] @ Wpf^T
    k_gemm<<<2500, 256, 0, stream>>>(ws + OFF_UPT, ws + OFF_WPF, ws + OFF_P1, nullptr, 150, 5);
    // Wuq[q][b][h] = Uq[q] @ Wqf^T
    k_gemm<<<320, 256, 0, stream>>>(ws + OFF_UQT, ws + OFF_WQF, ws + OFF_WUQ, nullptr, 150, 5);
    // GuT[t][j][b] = Up[t] @ Wg1^T  (bf16)
    k_gemm<<<8000, 256, 0, stream>>>(ws + OFF_UPT, ws + OFF_WG1, nullptr, GuT, 512, 16);
    // persistent scan
    k_scan<<<64, 256, 0, stream>>>(Uq, V, Wv, Wih, Whh, bih, bhh, ws, GuT, out);
}

// Round 2
// 9933.054 us; speedup vs baseline: 4.2835x; 4.2835x over previous
//
#include <hip/hip_runtime.h>
#include <hip/hip_fp16.h>

// LP=500, LQ=64, B=64, D=256, H=150
#define LP 500

typedef _Float16 h2f __attribute__((ext_vector_type(2)));

// ---------------- workspace layout (float slots) ----------------
constexpr size_t OFF_WVH2 = 0;         // [75][600] h2f  (Wv rows 0..149, Whh rows 150..599), 45000
constexpr size_t OFF_WGF2 = 45056;     // [128][512] h2f (folded Wg cc-part), 65536
constexpr size_t OFF_WIH2 = 110592;    // [256][452] h2f (Wih, pad 450..451 = 0), 115712
constexpr size_t OFF_WPF  = 226304;    // [150][256] f32 folded Wp
constexpr size_t OFF_WQF  = 264704;    // [150][256] f32 folded Wq
constexpr size_t OFF_WG1  = 303104;    // [512][256] f32 folded Wg u-part
constexpr size_t OFF_WUQ  = 434176;    // [64][64][150] f32  Wuq[q][b][h]
constexpr size_t OFF_P1   = 1048576;   // [500][64][150] f32 P1[t][b][h]
constexpr size_t OFF_GUH  = 5848576;   // [500][64][512] _Float16 Gu (8,192,000 slots)
constexpr size_t OFF_UPT  = 14040576;  // [500][256][64] f32
constexpr size_t OFF_UQT  = 22232576;  // [64][256][64] f32
constexpr size_t WS_FLOATS = 23281152; // ~93.1 MB

// ---------------- helpers ----------------
__device__ __forceinline__ float fast_rcp(float x) { return __builtin_amdgcn_rcpf(x); }
__device__ __forceinline__ float sigm(float x)   { return fast_rcp(1.f + __expf(-x)); }
__device__ __forceinline__ float tanh_f(float x) { return 1.f - 2.f * fast_rcp(1.f + __expf(2.f * x)); }

// ---------------- precompute: weight folds + f16 pair packs ----------------
__global__ __launch_bounds__(256) void k_prep(const float* __restrict__ Wp, const float* __restrict__ Wq,
                                              const float* __restrict__ Wg, const float* __restrict__ Wv,
                                              const float* __restrict__ Whh, const float* __restrict__ Wih,
                                              float* __restrict__ ws) {
    int i = blockIdx.x * 256 + threadIdx.x;
    if (i < 38400) { int h = i >> 8, d = i & 255; ws[OFF_WPF + i] = Wp[h * 512 + d] + Wp[h * 512 + 256 + d]; return; }
    i -= 38400;
    if (i < 38400) { int h = i >> 8, d = i & 255; ws[OFF_WQF + i] = Wq[h * 512 + d] + Wq[h * 512 + 256 + d]; return; }
    i -= 38400;
    if (i < 131072) { int j = i >> 8, d = i & 255; size_t r = (size_t)(512 + j) * 1024; ws[OFF_WG1 + i] = Wg[r + d] + Wg[r + 256 + d]; return; }
    i -= 131072;
    if (i < 45000) {  // Wvh2 [k2][600]
        int k2 = i / 600, m = i - k2 * 600;
        float lo, hi;
        if (m < 150) { lo = Wv[m * 150 + 2 * k2]; hi = Wv[m * 150 + 2 * k2 + 1]; }
        else { int mm = m - 150; lo = Whh[mm * 150 + 2 * k2]; hi = Whh[mm * 150 + 2 * k2 + 1]; }
        ((h2f*)(ws + OFF_WVH2))[i] = h2f{(_Float16)lo, (_Float16)hi};
        return;
    }
    i -= 45000;
    if (i < 65536) {  // Wgf2 [k2][512]
        int k2 = i >> 9, j = i & 511;
        int d = 2 * k2;
        size_t r = (size_t)(512 + j) * 1024;
        float lo = Wg[r + 512 + d] + Wg[r + 768 + d];
        float hi = Wg[r + 512 + d + 1] + Wg[r + 768 + d + 1];
        ((h2f*)(ws + OFF_WGF2))[i] = h2f{(_Float16)lo, (_Float16)hi};
        return;
    }
    i -= 65536;
    if (i < 115712) {  // Wih2 [k2][452]
        int k2 = i / 452, m = i - k2 * 452;
        float lo = 0.f, hi = 0.f;
        if (m < 450) { lo = Wih[m * 512 + 2 * k2]; hi = Wih[m * 512 + 2 * k2 + 1]; }
        ((h2f*)(ws + OFF_WIH2))[i] = h2f{(_Float16)lo, (_Float16)hi};
        return;
    }
}

// transpose X[t][64][256] -> XT[t][256][64], one block per t
__global__ __launch_bounds__(256) void k_tr(const float* __restrict__ X, float* __restrict__ XT) {
    __shared__ float tile[64][65];
    size_t base = (size_t)blockIdx.x * 16384;
    for (int ph = 0; ph < 4; ++ph) {
        for (int i = threadIdx.x; i < 4096; i += 256) {
            int b = i >> 6, dl = i & 63;
            tile[b][dl] = X[base + (size_t)b * 256 + ph * 64 + dl];
        }
        __syncthreads();
        for (int i = threadIdx.x; i < 4096; i += 256) {
            int d = i >> 6, bl = i & 63;
            XT[base + (size_t)(ph * 64 + d) * 64 + bl] = tile[bl][d];
        }
        __syncthreads();
    }
}

// acc[h,b] = sum_d XT[t,d,b]*Wf[h,d]; writes out[t][b][Hrows] as f32 or f16
__global__ __launch_bounds__(256) void k_gemm(const float* __restrict__ XT, const float* __restrict__ Wf,
                                              float* __restrict__ outF, _Float16* __restrict__ outH,
                                              int Hrows, int tilesPerT) {
    __shared__ float OL[64 * 33];
    int bidx = blockIdx.x;
    int t = bidx / tilesPerT, tile = bidx - t * tilesPerT;
    int w = threadIdx.x >> 6, lane = threadIdx.x & 63;
    int h0 = __builtin_amdgcn_readfirstlane(tile * 32 + w * 8);
    const float* x = XT + (size_t)t * 16384;
    float acc[8];
    const float* wr[8];
#pragma unroll
    for (int r = 0; r < 8; ++r) {
        int hr = h0 + r; if (hr >= Hrows) hr = Hrows - 1;
        wr[r] = Wf + (size_t)hr * 256;
        acc[r] = 0.f;
    }
    for (int d = 0; d < 256; d += 4) {
        float cv0 = x[(d + 0) * 64 + lane];
        float cv1 = x[(d + 1) * 64 + lane];
        float cv2 = x[(d + 2) * 64 + lane];
        float cv3 = x[(d + 3) * 64 + lane];
#pragma unroll
        for (int r = 0; r < 8; ++r) {
            float4 wv = *(const float4*)(wr[r] + d);
            acc[r] += cv0 * wv.x + cv1 * wv.y + cv2 * wv.z + cv3 * wv.w;
        }
    }
#pragma unroll
    for (int r = 0; r < 8; ++r) { int hl = w * 8 + r; OL[lane * 33 + hl] = acc[r]; }
    __syncthreads();
    int hbase = tile * 32;
    int nh = Hrows - hbase; if (nh > 32) nh = 32;
    for (int i = threadIdx.x; i < 64 * nh; i += 256) {
        int b = i / nh, hl = i - b * nh;
        float val = OL[b * 33 + hl];
        size_t idx = (size_t)t * 64 * Hrows + (size_t)b * Hrows + hbase + hl;
        if (outF) outF[idx] = val;
        else outH[idx] = (_Float16)val;
    }
}

// ---------------- per-batch persistent scan: 64 blocks x 512 threads, NO grid sync ----------------
__global__ __launch_bounds__(512) void k_scan2(
    const float* __restrict__ Uq, const float* __restrict__ V, const float* __restrict__ v0,
    const float* __restrict__ bih, const float* __restrict__ bhh,
    const float* __restrict__ ws, float* __restrict__ out) {
    __shared__ __attribute__((aligned(16))) _Float16 wuqh[64 * 152];
    __shared__ __attribute__((aligned(16))) _Float16 uqh[64 * 256];
    __shared__ __attribute__((aligned(16))) _Float16 vh[152];
    __shared__ __attribute__((aligned(16))) _Float16 pbh[152];
    __shared__ __attribute__((aligned(16))) _Float16 cch[256];
    __shared__ __attribute__((aligned(16))) _Float16 c_h[512];
    __shared__ float Vb[152];
    __shared__ float bihL[452];
    __shared__ float bhhL[452];
    __shared__ float vf[152];
    __shared__ float ghf[452];
    __shared__ float sa[64];
    __shared__ float ccf[256];
    __shared__ float gif[452];

    const int tid = threadIdx.x, b = blockIdx.x;
    const int w = tid >> 6, lane = tid & 63;
    const h2f* Wvh2 = (const h2f*)(ws + OFF_WVH2);
    const h2f* Wgf2 = (const h2f*)(ws + OFF_WGF2);
    const h2f* Wih2 = (const h2f*)(ws + OFF_WIH2);
    const float* WuqG = ws + OFF_WUQ;
    const float* P1 = ws + OFF_P1;
    const _Float16* GuH = (const _Float16*)(ws + OFF_GUH);

    // one-time per-b init
    for (int i = tid; i < 64 * 150; i += 512) { int q = i / 150, h = i - q * 150; wuqh[q * 152 + h] = (_Float16)WuqG[(size_t)q * 9600 + b * 150 + h]; }
    for (int i = tid; i < 64 * 256; i += 512) { int q = i >> 8, d = i & 255; uqh[i] = (_Float16)Uq[(size_t)q * 16384 + b * 256 + d]; }
    for (int i = tid; i < 150; i += 512) { Vb[i] = V[b * 150 + i]; float v = v0[b * 150 + i]; vf[i] = v; vh[i] = (_Float16)v; }
    for (int i = tid; i < 450; i += 512) { bihL[i] = bih[i]; bhhL[i] = bhh[i]; }
    __syncthreads();

    for (int t = 0; t < LP; ++t) {
        // ---- phase 1: m<150: pb = P1 + v@Wv^T ; m>=150: gh = v@Whh^T + bhh ----
        {
            const h2f* vh2 = (const h2f*)vh;
            for (int m = tid; m < 600; m += 512) {
                const h2f* wr = Wvh2 + m;
                float a0 = 0.f, a1 = 0.f;
#pragma unroll 4
                for (int k2 = 0; k2 < 74; k2 += 2) {
                    a0 = __builtin_amdgcn_fdot2(wr[(size_t)k2 * 600], vh2[k2], a0, false);
                    a1 = __builtin_amdgcn_fdot2(wr[(size_t)(k2 + 1) * 600], vh2[k2 + 1], a1, false);
                }
                a0 = __builtin_amdgcn_fdot2(wr[(size_t)74 * 600], vh2[74], a0, false);
                float acc = a0 + a1;
                if (m < 150) pbh[m] = (_Float16)(acc + P1[(size_t)t * 9600 + b * 150 + m]);
                else ghf[m - 150] = acc + bhhL[m - 150];
            }
        }
        __syncthreads();
        // ---- phase 2: s[q] = sum_h tanh(pb+wuq)*V ; softmax ; cc[d] ----
        {
            for (int q8 = 0; q8 < 8; ++q8) {
                int q = w * 8 + q8;
                float part = 0.f;
                for (int i = lane; i < 150; i += 64)
                    part += tanh_f((float)pbh[i] + (float)wuqh[q * 152 + i]) * Vb[i];
                part += __shfl_xor(part, 32); part += __shfl_xor(part, 16);
                part += __shfl_xor(part, 8);  part += __shfl_xor(part, 4);
                part += __shfl_xor(part, 2);  part += __shfl_xor(part, 1);
                if (lane == 0) sa[q] = part;
            }
        }
        __syncthreads();
        if (tid < 64) {
            float s = sa[tid];
            float m = s;
            m = fmaxf(m, __shfl_xor(m, 32)); m = fmaxf(m, __shfl_xor(m, 16));
            m = fmaxf(m, __shfl_xor(m, 8));  m = fmaxf(m, __shfl_xor(m, 4));
            m = fmaxf(m, __shfl_xor(m, 2));  m = fmaxf(m, __shfl_xor(m, 1));
            float e = __expf(s - m);
            float su = e;
            su += __shfl_xor(su, 32); su += __shfl_xor(su, 16); su += __shfl_xor(su, 8);
            su += __shfl_xor(su, 4);  su += __shfl_xor(su, 2);  su += __shfl_xor(su, 1);
            sa[tid] = e * fast_rcp(su);
        }
        __syncthreads();
        if (tid < 256) {
            float acc = 0.f;
#pragma unroll 8
            for (int q = 0; q < 64; ++q) acc += sa[q] * (float)uqh[q * 256 + tid];
            ccf[tid] = acc;
            cch[tid] = (_Float16)acc;
        }
        __syncthreads();
        // ---- phase 3: g[j] = sigm(Gu + cc@Wgf^T) ; c_[j] = g*cc2 ----
        {
            int j = tid;
            float acc = (float)GuH[(size_t)t * 32768 + b * 512 + j];
            const h2f* wg = Wgf2 + j;
            const h2f* cc2 = (const h2f*)cch;
            float a0 = 0.f, a1 = 0.f;
#pragma unroll 4
            for (int k2 = 0; k2 < 128; k2 += 2) {
                a0 = __builtin_amdgcn_fdot2(wg[(size_t)k2 * 512], cc2[k2], a0, false);
                a1 = __builtin_amdgcn_fdot2(wg[(size_t)(k2 + 1) * 512], cc2[k2 + 1], a1, false);
            }
            acc += a0 + a1;
            float g = sigm(acc);
            c_h[j] = (_Float16)(g * ccf[j & 255]);
        }
        __syncthreads();
        // ---- phase 4: gi[m] = c_ @ Wih^T ; GRU combine ----
        if (tid < 450) {
            const h2f* wr = Wih2 + tid;
            const h2f* cp2 = (const h2f*)c_h;
            float a0 = 0.f, a1 = 0.f;
#pragma unroll 4
            for (int k2 = 0; k2 < 256; k2 += 2) {
                a0 = __builtin_amdgcn_fdot2(wr[(size_t)k2 * 452], cp2[k2], a0, false);
                a1 = __builtin_amdgcn_fdot2(wr[(size_t)(k2 + 1) * 452], cp2[k2 + 1], a1, false);
            }
            gif[tid] = a0 + a1;
        }
        __syncthreads();
        if (tid < 150) {
            float r = sigm(gif[tid] + bihL[tid] + ghf[tid]);
            float z = sigm(gif[150 + tid] + bihL[150 + tid] + ghf[150 + tid]);
            float n = tanh_f(gif[300 + tid] + bihL[300 + tid] + r * ghf[300 + tid]);
            float vn = (1.f - z) * n + z * vf[tid];
            vf[tid] = vn;
            vh[tid] = (_Float16)vn;
            out[(size_t)t * 9600 + b * 150 + tid] = vn;
        }
        __syncthreads();
    }
}

// ---------------- launch ----------------
extern "C" void kernel_launch(void* const* d_in, const int* in_sizes, int n_in,
                              void* d_out, int out_size, void* d_ws, size_t ws_size,
                              hipStream_t stream) {
    const float* Up  = (const float*)d_in[0];
    const float* Uq  = (const float*)d_in[1];
    const float* Wp  = (const float*)d_in[2];
    const float* Wq  = (const float*)d_in[3];
    const float* Wv  = (const float*)d_in[4];
    const float* Wg  = (const float*)d_in[5];
    const float* V   = (const float*)d_in[6];
    const float* v0  = (const float*)d_in[7];
    const float* Wih = (const float*)d_in[8];
    const float* Whh = (const float*)d_in[9];
    const float* bih = (const float*)d_in[10];
    const float* bhh = (const float*)d_in[11];
    float* out = (float*)d_out;
    float* ws = (float*)d_ws;

    if (ws_size < WS_FLOATS * sizeof(float)) return;

    // weight folds + f16 packs (434,120 items)
    k_prep<<<1696, 256, 0, stream>>>(Wp, Wq, Wg, Wv, Whh, Wih, ws);
    // transposes for the big precompute GEMMs
    k_tr<<<500, 256, 0, stream>>>(Up, ws + OFF_UPT);
    k_tr<<<64, 256, 0, stream>>>(Uq, ws + OFF_UQT);
    // P1[t][b][h] = Up[t] @ Wpf^T  (f32)
    k_gemm<<<2500, 256, 0, stream>>>(ws + OFF_UPT, ws + OFF_WPF, ws + OFF_P1, nullptr, 150, 5);
    // Wuq[q][b][h] = Uq[q] @ Wqf^T (f32)
    k_gemm<<<320, 256, 0, stream>>>(ws + OFF_UQT, ws + OFF_WQF, ws + OFF_WUQ, nullptr, 150, 5);
    // Gu[t][b][j] = Up[t] @ Wg1^T  (f16)
    k_gemm<<<8000, 256, 0, stream>>>(ws + OFF_UPT, ws + OFF_WG1, nullptr, (_Float16*)(ws + OFF_GUH), 512, 16);
    // barrier-free per-batch scan
    k_scan2<<<64, 512, 0, stream>>>(Uq, V, v0, bih, bhh, ws, out);
}